// Round 6
// baseline (6738.797 us; speedup 1.0000x reference)
//
#include <hip/hip_runtime.h>

// LSTM on MI355X — persistent kernel, round 5.
// vs R4: barrier detection rebuilt. Blocks are 320 threads (4 compute waves +
// 1 extra wave). Wave 4 of block 0 is a dedicated aggregator: it alone scans
// the 256 per-block arrival flags and publishes a single `epoch` line; all
// other blocks poll just that one line (64 lanes, same address = 1 transaction
// per round). Poll LLC traffic drops ~256x. Numerics identical to R2-R4.

namespace {
constexpr int T_STEPS = 512;
constexpr int BATCH   = 64;
constexpr int DI      = 512;
constexpr int DL      = 1024;
constexpr int NKC     = 48;   // K=1536 in chunks of 32
constexpr int NKC_H   = 32;   // h-part chunks (K=1024)
constexpr int NBLK    = 256;  // grid == CU count, 1 block/CU resident
constexpr int NTHR    = 320;  // 4 compute waves + 1 aggregator wave
constexpr int FPAD    = 32;   // uints per flag slot (128 B padding)
constexpr int EPOCH_IDX = NBLK * FPAD;   // epoch line after the 256 flags
}

typedef __attribute__((ext_vector_type(8))) short bf16x8;
typedef __attribute__((ext_vector_type(8))) unsigned short u16x8;
typedef __attribute__((ext_vector_type(4))) float f32x4;
typedef __attribute__((ext_vector_type(4))) unsigned int u32x4;

__device__ __forceinline__ unsigned short f2bf(float x){
  unsigned int u = __float_as_uint(x);
  return (unsigned short)((u + 0x7FFFu + ((u >> 16) & 1u)) >> 16);
}
__device__ __forceinline__ float bf2f(unsigned short b){
  return __uint_as_float(((unsigned int)b) << 16);
}
__device__ __forceinline__ float fast_sigmoid(float v){
  return __fdividef(1.f, 1.f + __expf(-v));
}
__device__ __forceinline__ float fast_tanh(float v){
  v = fminf(fmaxf(v, -15.f), 15.f);
  float t = __expf(2.f * v);
  return __fdividef(t - 1.f, t + 1.f);
}

// ---------------- prep: embeddings -> bf16 [T*B][DI] ----------------
__global__ void prep_xe(const int* __restrict__ X, const float* __restrict__ emb,
                        unsigned short* __restrict__ xe){
  int i = blockIdx.x * blockDim.x + threadIdx.x;
  const int total = T_STEPS * BATCH * DI / 8;
  if (i >= total) return;
  int row = i >> 6;
  int seg = i & 63;
  int tok = X[row];
  const float* src = emb + (long long)tok * DI + seg * 8;
  float4 v0 = *(const float4*)src;
  float4 v1 = *(const float4*)(src + 4);
  u16x8 o;
  o[0]=f2bf(v0.x); o[1]=f2bf(v0.y); o[2]=f2bf(v0.z); o[3]=f2bf(v0.w);
  o[4]=f2bf(v1.x); o[5]=f2bf(v1.y); o[6]=f2bf(v1.z); o[7]=f2bf(v1.w);
  *(u16x8*)(xe + (long long)row * DI + seg * 8) = o;
}

// ---------------- prep: pack W into MFMA B-fragment layout, hi/lo ----------------
__global__ void prep_w(const float* __restrict__ Wf, const float* __restrict__ Wi,
                       const float* __restrict__ Wc, const float* __restrict__ Wo,
                       unsigned short* __restrict__ W_hi, unsigned short* __restrict__ W_lo){
  int idx = blockIdx.x * blockDim.x + threadIdx.x;
  if (idx >= 256 * NKC * 64) return;
  int lane = idx & 63;
  int kc   = (idx >> 6) % NKC;
  int bk   = idx / (64 * NKC);
  int lc = lane & 15, kg = lane >> 4;
  int g  = lc >> 2;
  int jl = bk * 4 + (lc & 3);
  const float* Wg = (g == 0) ? Wf : ((g == 1) ? Wi : ((g == 2) ? Wc : Wo));
  int kbase = kc * 32 + kg * 8;
  u16x8 hi, lo;
#pragma unroll
  for (int j = 0; j < 8; j++){
    float wv = Wg[(long long)(kbase + j) * DL + jl];
    unsigned short h = f2bf(wv);
    hi[j] = h;
    lo[j] = f2bf(wv - bf2f(h));
  }
  *(u16x8*)(W_hi + ((long long)(bk * NKC + kc) * 64 + lane) * 8) = hi;
  if (kc < NKC_H)
    *(u16x8*)(W_lo + ((long long)(bk * NKC_H + kc) * 64 + lane) * 8) = lo;
}

// ---------------- prep: h0 -> packed u32 plane, bias pack, flags zero ----------------
__global__ void prep_h(const float* __restrict__ h0,
                       const float* __restrict__ bf_, const float* __restrict__ bi_,
                       const float* __restrict__ bc_, const float* __restrict__ bo_,
                       unsigned int* __restrict__ hP,
                       float* __restrict__ bias_pack, unsigned int* __restrict__ bar){
  int i = blockIdx.x * blockDim.x + threadIdx.x;
  if (i < BATCH * DL){
    float v = h0[i];
    unsigned short hb = f2bf(v);
    unsigned short lb = f2bf(v - bf2f(hb));
    hP[i] = ((unsigned int)hb << 16) | (unsigned int)lb;
  }
  if (i < 4096){
    int r = i & 3, g = (i >> 2) & 3, bk = i >> 4;
    const float* bg = (g == 0) ? bf_ : ((g == 1) ? bi_ : ((g == 2) ? bc_ : bo_));
    bias_pack[i] = bg[bk * 4 + r];
  }
  if (i < (NBLK + 1) * FPAD) bar[i] = 0u;
}

// ---------------- persistent LSTM: all 512 steps in one kernel ----------------
__launch_bounds__(NTHR, 1)
__global__ void lstm_persist(const unsigned short* __restrict__ xe,
                             const unsigned short* __restrict__ W_hi,
                             const unsigned short* __restrict__ W_lo,
                             unsigned int* __restrict__ hP,        // [2][B*DL] packed hi|lo
                             const float* __restrict__ bias_pack,
                             float* __restrict__ out,
                             unsigned int* __restrict__ bar){
  extern __shared__ unsigned short lds[];
  unsigned short* lds_hi = lds;              // NKC  *512 elems (48 KB)
  unsigned short* lds_lo = lds + NKC * 512;  // NKC_H*512 elems (32 KB)
  __shared__ unsigned int stage_h[BATCH * 4];   // packed h slice [64 rows][4 cols]
  __shared__ float        stage_o[BATCH * 4];   // out slice
  const int tid  = threadIdx.x;
  const int bk   = blockIdx.x;
  const int w    = tid >> 6;
  const int lane = tid & 63;
  const bool isAgg     = (bk == 0) && (w == 4);   // dedicated aggregator wave
  const bool isCompute = (w < 4);

  // stage W once for the whole run (all 5 waves help)
  const uint4* srcHi = (const uint4*)(W_hi + (size_t)bk * NKC * 512);
  uint4* dHi = (uint4*)lds_hi;
  for (int i = tid; i < 3072; i += NTHR) dHi[i] = srcHi[i];
  const uint4* srcLo = (const uint4*)(W_lo + (size_t)bk * NKC_H * 512);
  uint4* dLo = (uint4*)lds_lo;
  for (int i = tid; i < 2048; i += NTHR) dLo[i] = srcLo[i];
  __syncthreads();

  const int lc = lane & 15;
  const int kg = lane >> 4;
  const int g  = lc >> 2;
  const int rowb = (w << 4) + lc;
  const float bias = bias_pack[bk * 16 + lc];
  const int srcBase = (lane & 48) | (lc & 3);
  const int hOff = rowb * DL + kg * 8;     // u32 elements
  const int xOff = rowb * DI + kg * 8;
  unsigned int* epochp = bar + EPOCH_IDX;
  float cr0 = 0.f, cr1 = 0.f, cr2 = 0.f, cr3 = 0.f;

  f32x4 acc0 = {0.f,0.f,0.f,0.f}, acc1 = {0.f,0.f,0.f,0.f};
  f32x4 acc2 = {0.f,0.f,0.f,0.f}, acc3 = {0.f,0.f,0.f,0.f};

#define XSTEP(KC, ACC) {                                                        \
    bf16x8 ax = *(const bf16x8*)(xRow + (KC) * 32);                             \
    bf16x8 bh = *(const bf16x8*)(lds_hi + (NKC_H + (KC)) * 512 + lane * 8);     \
    ACC = __builtin_amdgcn_mfma_f32_16x16x32_bf16(ax, bh, ACC, 0, 0, 0); }
// packed h: p[i] = hi_i<<16 | lo_i; unpack 8 elems -> ah (hi plane), al (lo plane)
#define HSTEP(KC, ACC) {                                                        \
    u32x4 p0 = *(const u32x4*)(hRow + (KC) * 32);                               \
    u32x4 p1 = *(const u32x4*)(hRow + (KC) * 32 + 4);                           \
    u32x4 ahu, alu;                                                             \
    ahu[0] = __builtin_amdgcn_perm(p0[1], p0[0], 0x07060302u);                  \
    ahu[1] = __builtin_amdgcn_perm(p0[3], p0[2], 0x07060302u);                  \
    ahu[2] = __builtin_amdgcn_perm(p1[1], p1[0], 0x07060302u);                  \
    ahu[3] = __builtin_amdgcn_perm(p1[3], p1[2], 0x07060302u);                  \
    alu[0] = __builtin_amdgcn_perm(p0[1], p0[0], 0x05040100u);                  \
    alu[1] = __builtin_amdgcn_perm(p0[3], p0[2], 0x05040100u);                  \
    alu[2] = __builtin_amdgcn_perm(p1[1], p1[0], 0x05040100u);                  \
    alu[3] = __builtin_amdgcn_perm(p1[3], p1[2], 0x05040100u);                  \
    bf16x8 ah = *(bf16x8*)&ahu;                                                 \
    bf16x8 al = *(bf16x8*)&alu;                                                 \
    bf16x8 bh = *(const bf16x8*)(lds_hi + (KC) * 512 + lane * 8);               \
    bf16x8 bl = *(const bf16x8*)(lds_lo + (KC) * 512 + lane * 8);               \
    ACC = __builtin_amdgcn_mfma_f32_16x16x32_bf16(ah, bh, ACC, 0, 0, 0);        \
    ACC = __builtin_amdgcn_mfma_f32_16x16x32_bf16(ah, bl, ACC, 0, 0, 0);        \
    ACC = __builtin_amdgcn_mfma_f32_16x16x32_bf16(al, bh, ACC, 0, 0, 0); }

  // x-part for step 0
  if (isCompute){
    const unsigned short* xRow = xe + xOff;
#pragma unroll
    for (int kc = 0; kc < 16; kc += 4){
      XSTEP(kc, acc0) XSTEP(kc + 1, acc1) XSTEP(kc + 2, acc2) XSTEP(kc + 3, acc3)
    }
  }

#pragma unroll 1
  for (int t = 0; t < T_STEPS; ++t){
    if (t > 0){
      if (isAgg){
        // scan all 256 arrival flags for step t, then publish the epoch
        const unsigned tgt = (unsigned)t;
        int spin = 0;
        for (;;){
          unsigned v0 = __hip_atomic_load(bar + (lane      ) * FPAD, __ATOMIC_RELAXED, __HIP_MEMORY_SCOPE_AGENT);
          unsigned v1 = __hip_atomic_load(bar + (lane +  64) * FPAD, __ATOMIC_RELAXED, __HIP_MEMORY_SCOPE_AGENT);
          unsigned v2 = __hip_atomic_load(bar + (lane + 128) * FPAD, __ATOMIC_RELAXED, __HIP_MEMORY_SCOPE_AGENT);
          unsigned v3 = __hip_atomic_load(bar + (lane + 192) * FPAD, __ATOMIC_RELAXED, __HIP_MEMORY_SCOPE_AGENT);
          bool ok = (v0 >= tgt) & (v1 >= tgt) & (v2 >= tgt) & (v3 >= tgt);
          if (__all(ok ? 1 : 0)) break;
          __builtin_amdgcn_s_sleep(1);
          if (++spin > (1 << 15)) break;   // bail loud (absmax), don't hang
        }
        if (lane == 0)
          __hip_atomic_store(epochp, tgt, __ATOMIC_RELAXED, __HIP_MEMORY_SCOPE_AGENT);
      } else if (w == 0){
        // wait for the single epoch line (all lanes same address = 1 txn)
        const unsigned tgt = (unsigned)t;
        int spin = 0;
        while (__hip_atomic_load(epochp, __ATOMIC_RELAXED, __HIP_MEMORY_SCOPE_AGENT) < tgt){
          __builtin_amdgcn_s_sleep(1);
          if (++spin > (1 << 16)) break;   // bail loud (absmax), don't hang
        }
        // invalidate stale L1/L2 copies of the reused h double-buffer
        __builtin_amdgcn_fence(__ATOMIC_ACQUIRE, "agent");
      }
    }
    __syncthreads();   // A: h_t visible to all compute waves

    const int rb = t & 1;
    const unsigned int* hRow = hP + rb * (BATCH * DL) + hOff;
    unsigned int* hPw = hP + (rb ^ 1) * (BATCH * DL);
    float* out_t = out + (size_t)t * BATCH * DL;

    if (isCompute){
      // ---- h-part: 3-term split-bf16 over K=1024, 4 chains ----
#pragma unroll
      for (int kc = 0; kc < NKC_H; kc += 4){
        HSTEP(kc, acc0) HSTEP(kc + 1, acc1) HSTEP(kc + 2, acc2) HSTEP(kc + 3, acc3)
      }
      f32x4 acc = (acc0 + acc1) + (acc2 + acc3);

      // ---- epilogue: gather f/i/c/o via shfl, gates, stage h/out into LDS ----
      float creg[4] = {cr0, cr1, cr2, cr3};
#pragma unroll
      for (int r = 0; r < 4; r++){
        float v = acc[r] + bias;
        float vF = __shfl(v, srcBase);
        float vI = __shfl(v, srcBase + 4);
        float vC = __shfl(v, srcBase + 8);
        float vO = __shfl(v, srcBase + 12);
        if (g == 0){
          int b = (w << 4) | (kg << 2) | r;
          float ft = fast_sigmoid(vF);
          float it = fast_sigmoid(vI);
          float gt = fast_tanh(vC);
          float ot = fast_sigmoid(vO);
          float cn = ft * creg[r] + it * gt;
          creg[r] = cn;
          float hn = ot * fast_tanh(cn);
          unsigned short hb = f2bf(hn);
          unsigned short lb = f2bf(hn - bf2f(hb));
          int si = (b << 2) | (lc & 3);
          stage_h[si] = ((unsigned int)hb << 16) | (unsigned int)lb;
          stage_o[si] = hn;
        }
      }
      cr0 = creg[0]; cr1 = creg[1]; cr2 = creg[2]; cr3 = creg[3];
    }

    __syncthreads();   // B: staging visible to wave 0

    // ---- wave 0: coalesced publish (64 x 16B), drain, set arrival flag ----
    if (w == 0){
      u32x4 hv = *(const u32x4*)&stage_h[lane << 2];
      u32x4 ov = *(const u32x4*)&stage_o[lane << 2];
      float4* odst = (float4*)(out_t + lane * DL + (bk << 2));
      *odst = *(const float4*)&ov;                       // plain (host-read only)
      unsigned int* hdst = hPw + lane * DL + (bk << 2);
      asm volatile("global_store_dwordx4 %0, %1, off sc0 sc1"
                   :: "v"(hdst), "v"(hv) : "memory");
      asm volatile("s_waitcnt vmcnt(0)" ::: "memory");
      __builtin_amdgcn_sched_barrier(0);
      if (tid == 0)
        __hip_atomic_store(bar + bk * FPAD, (unsigned)(t + 1),
                           __ATOMIC_RELAXED, __HIP_MEMORY_SCOPE_AGENT);
    }

    // ---- overlap: x-part MFMAs for step t+1 (xe independent of h) ----
    acc0 = (f32x4){0.f,0.f,0.f,0.f}; acc1 = (f32x4){0.f,0.f,0.f,0.f};
    acc2 = (f32x4){0.f,0.f,0.f,0.f}; acc3 = (f32x4){0.f,0.f,0.f,0.f};
    if (isCompute && t + 1 < T_STEPS){
      const unsigned short* xRow = xe + (size_t)(t + 1) * BATCH * DI + xOff;
#pragma unroll
      for (int kc = 0; kc < 16; kc += 4){
        XSTEP(kc, acc0) XSTEP(kc + 1, acc1) XSTEP(kc + 2, acc2) XSTEP(kc + 3, acc3)
      }
    }
  }
#undef XSTEP
#undef HSTEP
}

extern "C" void kernel_launch(void* const* d_in, const int* in_sizes, int n_in,
                              void* d_out, int out_size, void* d_ws, size_t ws_size,
                              hipStream_t stream){
  const int*   X   = (const int*)d_in[0];
  const float* h0  = (const float*)d_in[1];
  const float* emb = (const float*)d_in[2];
  const float* Wf  = (const float*)d_in[3];
  const float* bf_ = (const float*)d_in[4];
  const float* Wi  = (const float*)d_in[5];
  const float* bi_ = (const float*)d_in[6];
  const float* Wc  = (const float*)d_in[7];
  const float* bc_ = (const float*)d_in[8];
  const float* Wo  = (const float*)d_in[9];
  const float* bo_ = (const float*)d_in[10];
  float* out = (float*)d_out;

  char* ws = (char*)d_ws;
  size_t off = 0;
  auto alloc = [&](size_t bytes) -> void* {
    void* p = ws + off;
    off = (off + bytes + 255) & ~((size_t)255);
    return p;
  };
  unsigned short* xe        = (unsigned short*)alloc(sizeof(unsigned short) * (size_t)T_STEPS * BATCH * DI);
  unsigned short* W_hi      = (unsigned short*)alloc(sizeof(unsigned short) * (size_t)256 * NKC * 512);
  unsigned short* W_lo      = (unsigned short*)alloc(sizeof(unsigned short) * (size_t)256 * NKC_H * 512);
  unsigned int*   hP        = (unsigned int*)alloc(sizeof(unsigned int) * 2 * BATCH * DL);
  float*          bias_pack = (float*)alloc(sizeof(float) * 4096);
  unsigned int*   bar       = (unsigned int*)alloc(sizeof(unsigned int) * (NBLK + 1) * FPAD);
  (void)ws_size; (void)in_sizes; (void)n_in; (void)out_size;

  static bool attr_set = false;
  if (!attr_set){
    hipFuncSetAttribute((const void*)lstm_persist,
                        hipFuncAttributeMaxDynamicSharedMemorySize, 160 * 1024);
    attr_set = true;
  }

  hipLaunchKernelGGL(prep_xe, dim3(8192), dim3(256), 0, stream, X, emb, xe);
  hipLaunchKernelGGL(prep_w,  dim3(3072), dim3(256), 0, stream, Wf, Wi, Wc, Wo, W_hi, W_lo);
  hipLaunchKernelGGL(prep_h,  dim3(256),  dim3(256), 0, stream, h0, bf_, bi_, bc_, bo_,
                     hP, bias_pack, bar);
  hipLaunchKernelGGL(lstm_persist, dim3(NBLK), dim3(NTHR), 80 * 1024, stream,
                     xe, W_hi, W_lo, hP, bias_pack, out, bar);
}

// Round 7
// 4537.281 us; speedup vs baseline: 1.4852x; 1.4852x over previous
//
#include <hip/hip_runtime.h>

// LSTM on MI355X — persistent kernel, round 6.
// vs R5: ZERO cache invalidates. h-state reads/writes go through the coherence
// point (LLC) via sc0 sc1 loads/stores -> no acquire fence, no buffer_inv, no
// per-step L2 invalidation storm (R3-R5's shared bottleneck theory). h is now a
// single bf16 plane (halves LLC traffic + h-part MFMAs; absmax predicted to
// rise ~2-6e-3, within threshold). All 32 h-loads pre-issued per step, one
// vmcnt(0), then pure LDS+MFMA. Barrier detection (aggregator+epoch) from R5.

namespace {
constexpr int T_STEPS = 512;
constexpr int BATCH   = 64;
constexpr int DI      = 512;
constexpr int DL      = 1024;
constexpr int NKC     = 48;   // K=1536 in chunks of 32
constexpr int NKC_H   = 32;   // h-part chunks (K=1024)
constexpr int NBLK    = 256;  // grid == CU count, 1 block/CU resident
constexpr int NTHR    = 320;  // 4 compute waves + 1 aggregator wave
constexpr int FPAD    = 32;   // uints per flag slot (128 B padding)
constexpr int EPOCH_IDX = NBLK * FPAD;
}

typedef __attribute__((ext_vector_type(8))) short bf16x8;
typedef __attribute__((ext_vector_type(8))) unsigned short u16x8;
typedef __attribute__((ext_vector_type(4))) float f32x4;
typedef __attribute__((ext_vector_type(4))) unsigned int u32x4;
typedef __attribute__((ext_vector_type(2))) unsigned int u32x2;

__device__ __forceinline__ unsigned short f2bf(float x){
  unsigned int u = __float_as_uint(x);
  return (unsigned short)((u + 0x7FFFu + ((u >> 16) & 1u)) >> 16);
}
__device__ __forceinline__ float bf2f(unsigned short b){
  return __uint_as_float(((unsigned int)b) << 16);
}
__device__ __forceinline__ float fast_sigmoid(float v){
  return __fdividef(1.f, 1.f + __expf(-v));
}
__device__ __forceinline__ float fast_tanh(float v){
  v = fminf(fmaxf(v, -15.f), 15.f);
  float t = __expf(2.f * v);
  return __fdividef(t - 1.f, t + 1.f);
}

// ---------------- prep: embeddings -> bf16 [T*B][DI] ----------------
__global__ void prep_xe(const int* __restrict__ X, const float* __restrict__ emb,
                        unsigned short* __restrict__ xe){
  int i = blockIdx.x * blockDim.x + threadIdx.x;
  const int total = T_STEPS * BATCH * DI / 8;
  if (i >= total) return;
  int row = i >> 6;
  int seg = i & 63;
  int tok = X[row];
  const float* src = emb + (long long)tok * DI + seg * 8;
  float4 v0 = *(const float4*)src;
  float4 v1 = *(const float4*)(src + 4);
  u16x8 o;
  o[0]=f2bf(v0.x); o[1]=f2bf(v0.y); o[2]=f2bf(v0.z); o[3]=f2bf(v0.w);
  o[4]=f2bf(v1.x); o[5]=f2bf(v1.y); o[6]=f2bf(v1.z); o[7]=f2bf(v1.w);
  *(u16x8*)(xe + (long long)row * DI + seg * 8) = o;
}

// ---------------- prep: pack W into MFMA B-fragment layout, hi/lo ----------------
__global__ void prep_w(const float* __restrict__ Wf, const float* __restrict__ Wi,
                       const float* __restrict__ Wc, const float* __restrict__ Wo,
                       unsigned short* __restrict__ W_hi, unsigned short* __restrict__ W_lo){
  int idx = blockIdx.x * blockDim.x + threadIdx.x;
  if (idx >= 256 * NKC * 64) return;
  int lane = idx & 63;
  int kc   = (idx >> 6) % NKC;
  int bk   = idx / (64 * NKC);
  int lc = lane & 15, kg = lane >> 4;
  int g  = lc >> 2;
  int jl = bk * 4 + (lc & 3);
  const float* Wg = (g == 0) ? Wf : ((g == 1) ? Wi : ((g == 2) ? Wc : Wo));
  int kbase = kc * 32 + kg * 8;
  u16x8 hi, lo;
#pragma unroll
  for (int j = 0; j < 8; j++){
    float wv = Wg[(long long)(kbase + j) * DL + jl];
    unsigned short h = f2bf(wv);
    hi[j] = h;
    lo[j] = f2bf(wv - bf2f(h));
  }
  *(u16x8*)(W_hi + ((long long)(bk * NKC + kc) * 64 + lane) * 8) = hi;
  if (kc < NKC_H)
    *(u16x8*)(W_lo + ((long long)(bk * NKC_H + kc) * 64 + lane) * 8) = lo;
}

// ---------------- prep: h0 -> bf16 plane, bias pack, flags zero ----------------
__global__ void prep_h(const float* __restrict__ h0,
                       const float* __restrict__ bf_, const float* __restrict__ bi_,
                       const float* __restrict__ bc_, const float* __restrict__ bo_,
                       unsigned short* __restrict__ hB,
                       float* __restrict__ bias_pack, unsigned int* __restrict__ bar){
  int i = blockIdx.x * blockDim.x + threadIdx.x;
  if (i < BATCH * DL) hB[i] = f2bf(h0[i]);
  if (i < 4096){
    int r = i & 3, g = (i >> 2) & 3, bk = i >> 4;
    const float* bg = (g == 0) ? bf_ : ((g == 1) ? bi_ : ((g == 2) ? bc_ : bo_));
    bias_pack[i] = bg[bk * 4 + r];
  }
  if (i < (NBLK + 1) * FPAD) bar[i] = 0u;
}

// ---------------- persistent LSTM: all 512 steps in one kernel ----------------
__launch_bounds__(NTHR, 1)
__global__ void lstm_persist(const unsigned short* __restrict__ xe,
                             const unsigned short* __restrict__ W_hi,
                             const unsigned short* __restrict__ W_lo,
                             unsigned short* __restrict__ hB,     // [2][B*DL] bf16
                             const float* __restrict__ bias_pack,
                             float* __restrict__ out,
                             unsigned int* __restrict__ bar){
  extern __shared__ unsigned short lds[];
  unsigned short* lds_hi = lds;              // NKC  *512 elems (48 KB)
  unsigned short* lds_lo = lds + NKC * 512;  // NKC_H*512 elems (32 KB)
  __shared__ unsigned short stage_h[BATCH * 4];  // bf16 h slice [64 rows][4 cols]
  __shared__ float          stage_o[BATCH * 4];  // out slice
  const int tid  = threadIdx.x;
  const int bk   = blockIdx.x;
  const int w    = tid >> 6;
  const int lane = tid & 63;
  const bool isAgg     = (bk == 0) && (w == 4);
  const bool isCompute = (w < 4);

  // stage W once for the whole run (all 5 waves help)
  const uint4* srcHi = (const uint4*)(W_hi + (size_t)bk * NKC * 512);
  uint4* dHi = (uint4*)lds_hi;
  for (int i = tid; i < 3072; i += NTHR) dHi[i] = srcHi[i];
  const uint4* srcLo = (const uint4*)(W_lo + (size_t)bk * NKC_H * 512);
  uint4* dLo = (uint4*)lds_lo;
  for (int i = tid; i < 2048; i += NTHR) dLo[i] = srcLo[i];
  __syncthreads();

  const int lc = lane & 15;
  const int kg = lane >> 4;
  const int g  = lc >> 2;
  const int rowb = (w << 4) + lc;
  const float bias = bias_pack[bk * 16 + lc];
  const int srcBase = (lane & 48) | (lc & 3);
  const int hOff = rowb * DL + kg * 8;     // u16 elements
  const int xOff = rowb * DI + kg * 8;
  unsigned int* epochp = bar + EPOCH_IDX;
  float cr0 = 0.f, cr1 = 0.f, cr2 = 0.f, cr3 = 0.f;

  f32x4 acc0 = {0.f,0.f,0.f,0.f}, acc1 = {0.f,0.f,0.f,0.f};
  f32x4 acc2 = {0.f,0.f,0.f,0.f}, acc3 = {0.f,0.f,0.f,0.f};

#define XSTEP(KC, ACC) {                                                        \
    bf16x8 ax = *(const bf16x8*)(xRow + (KC) * 32);                             \
    bf16x8 bh = *(const bf16x8*)(lds_hi + (NKC_H + (KC)) * 512 + lane * 8);     \
    ACC = __builtin_amdgcn_mfma_f32_16x16x32_bf16(ax, bh, ACC, 0, 0, 0); }
// consume pre-loaded h frag hv[KC]: 2-term (h_bf16 * (W_hi + W_lo))
#define HSTEP2(KC, ACC) {                                                       \
    bf16x8 ah = *(const bf16x8*)&hv[KC];                                        \
    bf16x8 bh = *(const bf16x8*)(lds_hi + (KC) * 512 + lane * 8);               \
    bf16x8 bl = *(const bf16x8*)(lds_lo + (KC) * 512 + lane * 8);               \
    ACC = __builtin_amdgcn_mfma_f32_16x16x32_bf16(ah, bh, ACC, 0, 0, 0);        \
    ACC = __builtin_amdgcn_mfma_f32_16x16x32_bf16(ah, bl, ACC, 0, 0, 0); }
// coherent (LLC-served) 16B load: base + literal byte offset, bypass L1+L2
#define LOADH(I, OFFSTR)                                                        \
    asm volatile("global_load_dwordx4 %0, %1, off offset:" OFFSTR " sc0 sc1"    \
                 : "=v"(hv[I]) : "v"(hbase));

  // x-part for step 0
  if (isCompute){
    const unsigned short* xRow = xe + xOff;
#pragma unroll
    for (int kc = 0; kc < 16; kc += 4){
      XSTEP(kc, acc0) XSTEP(kc + 1, acc1) XSTEP(kc + 2, acc2) XSTEP(kc + 3, acc3)
    }
  }

#pragma unroll 1
  for (int t = 0; t < T_STEPS; ++t){
    if (t > 0){
      if (isAgg){
        // scan all 256 arrival flags for step t, then publish the epoch
        const unsigned tgt = (unsigned)t;
        int spin = 0;
        for (;;){
          unsigned v0 = __hip_atomic_load(bar + (lane      ) * FPAD, __ATOMIC_RELAXED, __HIP_MEMORY_SCOPE_AGENT);
          unsigned v1 = __hip_atomic_load(bar + (lane +  64) * FPAD, __ATOMIC_RELAXED, __HIP_MEMORY_SCOPE_AGENT);
          unsigned v2 = __hip_atomic_load(bar + (lane + 128) * FPAD, __ATOMIC_RELAXED, __HIP_MEMORY_SCOPE_AGENT);
          unsigned v3 = __hip_atomic_load(bar + (lane + 192) * FPAD, __ATOMIC_RELAXED, __HIP_MEMORY_SCOPE_AGENT);
          bool ok = (v0 >= tgt) & (v1 >= tgt) & (v2 >= tgt) & (v3 >= tgt);
          if (__all(ok ? 1 : 0)) break;
          __builtin_amdgcn_s_sleep(1);
          if (++spin > (1 << 15)) break;   // bail loud (absmax), don't hang
        }
        if (lane == 0)
          __hip_atomic_store(epochp, tgt, __ATOMIC_RELAXED, __HIP_MEMORY_SCOPE_AGENT);
      } else if (w == 0){
        // wait for the single epoch line (all lanes same address = 1 txn)
        const unsigned tgt = (unsigned)t;
        int spin = 0;
        while (__hip_atomic_load(epochp, __ATOMIC_RELAXED, __HIP_MEMORY_SCOPE_AGENT) < tgt){
          __builtin_amdgcn_s_sleep(1);
          if (++spin > (1 << 16)) break;   // bail loud (absmax), don't hang
        }
        // NO acquire fence: h reads below bypass L1/L2 (sc0 sc1), always fresh
      }
    }
    __syncthreads();   // A: epoch observed -> all waves may read h_t

    const int rb = t & 1;
    unsigned short* hWr = hB + (rb ^ 1) * (BATCH * DL);
    float* out_t = out + (size_t)t * BATCH * DL;

    if (isCompute){
      // ---- pre-issue all 32 coherent h loads (16B each, stride 64B) ----
      u32x4 hv[32];
      const unsigned short* hbase = hB + rb * (BATCH * DL) + hOff;
      LOADH( 0,"0")    LOADH( 1,"64")   LOADH( 2,"128")  LOADH( 3,"192")
      LOADH( 4,"256")  LOADH( 5,"320")  LOADH( 6,"384")  LOADH( 7,"448")
      LOADH( 8,"512")  LOADH( 9,"576")  LOADH(10,"640")  LOADH(11,"704")
      LOADH(12,"768")  LOADH(13,"832")  LOADH(14,"896")  LOADH(15,"960")
      LOADH(16,"1024") LOADH(17,"1088") LOADH(18,"1152") LOADH(19,"1216")
      LOADH(20,"1280") LOADH(21,"1344") LOADH(22,"1408") LOADH(23,"1472")
      LOADH(24,"1536") LOADH(25,"1600") LOADH(26,"1664") LOADH(27,"1728")
      LOADH(28,"1792") LOADH(29,"1856") LOADH(30,"1920") LOADH(31,"1984")
      asm volatile("s_waitcnt vmcnt(0)" ::: "memory");
      __builtin_amdgcn_sched_barrier(0);

      // ---- h-part: 2-term bf16 over K=1024, 4 chains ----
#pragma unroll
      for (int kc = 0; kc < NKC_H; kc += 4){
        HSTEP2(kc, acc0) HSTEP2(kc + 1, acc1) HSTEP2(kc + 2, acc2) HSTEP2(kc + 3, acc3)
      }
      f32x4 acc = (acc0 + acc1) + (acc2 + acc3);

      // ---- epilogue: gather f/i/c/o via shfl, gates, stage h/out into LDS ----
      float creg[4] = {cr0, cr1, cr2, cr3};
#pragma unroll
      for (int r = 0; r < 4; r++){
        float v = acc[r] + bias;
        float vF = __shfl(v, srcBase);
        float vI = __shfl(v, srcBase + 4);
        float vC = __shfl(v, srcBase + 8);
        float vO = __shfl(v, srcBase + 12);
        if (g == 0){
          int b = (w << 4) | (kg << 2) | r;
          float ft = fast_sigmoid(vF);
          float it = fast_sigmoid(vI);
          float gt = fast_tanh(vC);
          float ot = fast_sigmoid(vO);
          float cn = ft * creg[r] + it * gt;
          creg[r] = cn;
          float hn = ot * fast_tanh(cn);
          int si = (b << 2) | (lc & 3);
          stage_h[si] = f2bf(hn);
          stage_o[si] = hn;
        }
      }
      cr0 = creg[0]; cr1 = creg[1]; cr2 = creg[2]; cr3 = creg[3];
    }

    __syncthreads();   // B: staging visible to wave 0

    // ---- wave 0: coalesced publish, drain, set arrival flag ----
    if (w == 0){
      u32x2 hv2 = *(const u32x2*)&stage_h[lane << 2];        // 8B = one row's 4 cols
      u32x4 ov  = *(const u32x4*)&stage_o[lane << 2];
      float4* odst = (float4*)(out_t + lane * DL + (bk << 2));
      *odst = *(const float4*)&ov;                           // plain (host-read only)
      unsigned short* hdst = hWr + lane * DL + (bk << 2);
      asm volatile("global_store_dwordx2 %0, %1, off sc0 sc1"
                   :: "v"(hdst), "v"(hv2) : "memory");
      asm volatile("s_waitcnt vmcnt(0)" ::: "memory");
      __builtin_amdgcn_sched_barrier(0);
      if (tid == 0)
        __hip_atomic_store(bar + bk * FPAD, (unsigned)(t + 1),
                           __ATOMIC_RELAXED, __HIP_MEMORY_SCOPE_AGENT);
    }

    // ---- overlap: x-part MFMAs for step t+1 (xe independent of h) ----
    acc0 = (f32x4){0.f,0.f,0.f,0.f}; acc1 = (f32x4){0.f,0.f,0.f,0.f};
    acc2 = (f32x4){0.f,0.f,0.f,0.f}; acc3 = (f32x4){0.f,0.f,0.f,0.f};
    if (isCompute && t + 1 < T_STEPS){
      const unsigned short* xRow = xe + (size_t)(t + 1) * BATCH * DI + xOff;
#pragma unroll
      for (int kc = 0; kc < 16; kc += 4){
        XSTEP(kc, acc0) XSTEP(kc + 1, acc1) XSTEP(kc + 2, acc2) XSTEP(kc + 3, acc3)
      }
    }
  }
#undef XSTEP
#undef HSTEP2
#undef LOADH
}

extern "C" void kernel_launch(void* const* d_in, const int* in_sizes, int n_in,
                              void* d_out, int out_size, void* d_ws, size_t ws_size,
                              hipStream_t stream){
  const int*   X   = (const int*)d_in[0];
  const float* h0  = (const float*)d_in[1];
  const float* emb = (const float*)d_in[2];
  const float* Wf  = (const float*)d_in[3];
  const float* bf_ = (const float*)d_in[4];
  const float* Wi  = (const float*)d_in[5];
  const float* bi_ = (const float*)d_in[6];
  const float* Wc  = (const float*)d_in[7];
  const float* bc_ = (const float*)d_in[8];
  const float* Wo  = (const float*)d_in[9];
  const float* bo_ = (const float*)d_in[10];
  float* out = (float*)d_out;

  char* ws = (char*)d_ws;
  size_t off = 0;
  auto alloc = [&](size_t bytes) -> void* {
    void* p = ws + off;
    off = (off + bytes + 255) & ~((size_t)255);
    return p;
  };
  unsigned short* xe        = (unsigned short*)alloc(sizeof(unsigned short) * (size_t)T_STEPS * BATCH * DI);
  unsigned short* W_hi      = (unsigned short*)alloc(sizeof(unsigned short) * (size_t)256 * NKC * 512);
  unsigned short* W_lo      = (unsigned short*)alloc(sizeof(unsigned short) * (size_t)256 * NKC_H * 512);
  unsigned short* hB        = (unsigned short*)alloc(sizeof(unsigned short) * 2 * BATCH * DL);
  float*          bias_pack = (float*)alloc(sizeof(float) * 4096);
  unsigned int*   bar       = (unsigned int*)alloc(sizeof(unsigned int) * (NBLK + 1) * FPAD);
  (void)ws_size; (void)in_sizes; (void)n_in; (void)out_size;

  static bool attr_set = false;
  if (!attr_set){
    hipFuncSetAttribute((const void*)lstm_persist,
                        hipFuncAttributeMaxDynamicSharedMemorySize, 160 * 1024);
    attr_set = true;
  }

  hipLaunchKernelGGL(prep_xe, dim3(8192), dim3(256), 0, stream, X, emb, xe);
  hipLaunchKernelGGL(prep_w,  dim3(3072), dim3(256), 0, stream, Wf, Wi, Wc, Wo, W_hi, W_lo);
  hipLaunchKernelGGL(prep_h,  dim3(256),  dim3(256), 0, stream, h0, bf_, bi_, bc_, bo_,
                     hB, bias_pack, bar);
  hipLaunchKernelGGL(lstm_persist, dim3(NBLK), dim3(NTHR), 80 * 1024, stream,
                     xe, W_hi, W_lo, hB, bias_pack, out, bar);
}